// Round 2
// baseline (699.848 us; speedup 1.0000x reference)
//
#include <hip/hip_runtime.h>

#define NT 8192
#define DD 1024
#define HH 4096
#define EE 8

typedef __attribute__((ext_vector_type(8))) short short8;
typedef __attribute__((ext_vector_type(4))) float f32x4;

__device__ __forceinline__ unsigned short f2bf(float f) {
    unsigned int u = __float_as_uint(f);
    u += 0x7FFFu + ((u >> 16) & 1u);   // round-to-nearest-even
    return (unsigned short)(u >> 16);
}

__device__ __forceinline__ void gload_lds16(const void* g, void* l) {
    __builtin_amdgcn_global_load_lds(
        (const __attribute__((address_space(1))) unsigned int*)g,
        (__attribute__((address_space(3))) unsigned int*)l, 16, 0, 0);
}

// ---- fp32 -> bf16 convert for BOTH weight tensors in one launch ----
__global__ __launch_bounds__(256) void cvtw_kernel(const float* __restrict__ a,
                                                   const float* __restrict__ b,
                                                   unsigned short* __restrict__ da,
                                                   unsigned short* __restrict__ db) {
    const size_t half = (size_t)EE * HH * DD;
    size_t i = ((size_t)blockIdx.x * 256 + threadIdx.x) * 4;
    const float* s; unsigned short* d;
    if (i < half) { s = a + i; d = da + i; }
    else          { s = b + (i - half); d = db + (i - half); }
    float4 v = *(const float4*)s;
    ushort4 o;
    o.x = f2bf(v.x); o.y = f2bf(v.y); o.z = f2bf(v.z); o.w = f2bf(v.w);
    *(ushort4*)d = o;
}

// ---- router: one wave per token; argmax of x @ Wr^T + br ----
__global__ __launch_bounds__(256) void router_kernel(const float* __restrict__ x,
                                                     const float* __restrict__ Wr,
                                                     const float* __restrict__ br,
                                                     int* __restrict__ counts,
                                                     int* __restrict__ tlist) {
    __shared__ float sW[EE * DD];  // 32 KB
    const int t = threadIdx.x;
    for (int i = t; i < EE * DD / 4; i += 256)
        ((float4*)sW)[i] = ((const float4*)Wr)[i];
    __syncthreads();
    const int lane = t & 63;
    const int wv = t >> 6;
    const int token = blockIdx.x * 4 + wv;
    const float* xr = x + (size_t)token * DD;
    float acc[EE];
#pragma unroll
    for (int e = 0; e < EE; e++) acc[e] = 0.f;
    for (int k = lane; k < DD; k += 64) {
        float xv = xr[k];
#pragma unroll
        for (int e = 0; e < EE; e++) acc[e] += xv * sW[e * DD + k];
    }
#pragma unroll
    for (int off = 32; off > 0; off >>= 1) {
#pragma unroll
        for (int e = 0; e < EE; e++) acc[e] += __shfl_xor(acc[e], off);
    }
    if (lane == 0) {
        int best = 0;
        float bv = acc[0] + br[0];
#pragma unroll
        for (int e = 1; e < EE; e++) {
            float v = acc[e] + br[e];
            if (v > bv) { bv = v; best = e; }   // strict > == first-max (jnp.argmax)
        }
        int pos = atomicAdd(&counts[best], 1);
        tlist[best * NT + pos] = token;
    }
}

__global__ void offsets_kernel(const int* __restrict__ counts, int* __restrict__ offsets) {
    if (threadIdx.x == 0) {
        int s = 0;
        for (int e = 0; e < EE; e++) { offsets[e] = s; s += counts[e]; }
    }
}

// ---- gather x rows into expert-sorted order, fp32 -> bf16 ----
// row i of xg corresponds to expert-sorted position i (offsets/tlist order).
__global__ __launch_bounds__(256) void gather_kernel(const float* __restrict__ x,
                                                     const int* __restrict__ tlist,
                                                     const int* __restrict__ offsets,
                                                     unsigned short* __restrict__ xg) {
    const int row = blockIdx.x * 4 + (threadIdx.x >> 6);
    const int lane = threadIdx.x & 63;
    int e = 0;
#pragma unroll
    for (int k = 1; k < EE; k++)
        if (row >= offsets[k]) e = k;
    const int token = tlist[e * NT + row - offsets[e]];
    const float4* src = (const float4*)(x + (size_t)token * DD);
    ushort4* dst = (ushort4*)(xg + (size_t)row * DD);
#pragma unroll
    for (int it = 0; it < 4; it++) {
        float4 v = src[it * 64 + lane];
        ushort4 o;
        o.x = f2bf(v.x); o.y = f2bf(v.y); o.z = f2bf(v.z); o.w = f2bf(v.w);
        dst[it * 64 + lane] = o;
    }
}

// ---- up GEMM: h = silu(xg @ Wup[e]^T + bup[e]), contiguous A, bf16 out ----
__global__ __launch_bounds__(256) void up_gemm(const unsigned short* __restrict__ xg,
                                               const unsigned short* __restrict__ Wub,
                                               const float* __restrict__ bup,
                                               const int* __restrict__ counts,
                                               const int* __restrict__ offsets,
                                               unsigned short* __restrict__ hbuf) {
    const int e = blockIdx.z;
    const int cnt = counts[e];
    const int m0 = blockIdx.y * 128;
    if (m0 >= cnt) return;
    const int n0 = blockIdx.x * 128;
    const int t = threadIdx.x;
    const int off_e = offsets[e];

    __shared__ unsigned short sA[128 * 32];
    __shared__ unsigned short sB[128 * 32];

    const int r0 = t >> 2;   // row within 64-row half
    const int kc = t & 3;    // 8-elem chunk within BK=32
    const int c1 = cnt - 1;
    int ra = m0 + r0;      if (ra > c1) ra = c1;   // clamp tail rows (masked on store)
    int rb = m0 + 64 + r0; if (rb > c1) rb = c1;
    const unsigned short* gA0 = xg + (size_t)(off_e + ra) * DD + kc * 8;
    const unsigned short* gA1 = xg + (size_t)(off_e + rb) * DD + kc * 8;
    const unsigned short* gB0 = Wub + ((size_t)e * HH + n0 + r0) * DD + kc * 8;
    const unsigned short* gB1 = Wub + ((size_t)e * HH + n0 + 64 + r0) * DD + kc * 8;
    unsigned short* lA0 = sA + t * 8;
    unsigned short* lA1 = sA + (t + 256) * 8;
    unsigned short* lB0 = sB + t * 8;
    unsigned short* lB1 = sB + (t + 256) * 8;

    const int lane = t & 63;
    const int wm = ((t >> 6) & 1) * 64;
    const int wn = (t >> 7) * 64;
    const int mrow = lane & 15;
    const int kq = lane >> 4;

    f32x4 acc[4][4];
#pragma unroll
    for (int i = 0; i < 4; i++)
#pragma unroll
        for (int j = 0; j < 4; j++)
            acc[i][j] = (f32x4){0.f, 0.f, 0.f, 0.f};

    for (int kt = 0; kt < DD; kt += 32) {
        __syncthreads();
        gload_lds16(gA0 + kt, lA0);
        gload_lds16(gA1 + kt, lA1);
        gload_lds16(gB0 + kt, lB0);
        gload_lds16(gB1 + kt, lB1);
        __syncthreads();
        short8 a[4], b[4];
#pragma unroll
        for (int i = 0; i < 4; i++) {
            a[i] = *(const short8*)(sA + (wm + i * 16 + mrow) * 32 + kq * 8);
            b[i] = *(const short8*)(sB + (wn + i * 16 + mrow) * 32 + kq * 8);
        }
#pragma unroll
        for (int i = 0; i < 4; i++)
#pragma unroll
            for (int j = 0; j < 4; j++)
                acc[i][j] = __builtin_amdgcn_mfma_f32_16x16x32_bf16(a[i], b[j], acc[i][j], 0, 0, 0);
    }

    float bias[4];
#pragma unroll
    for (int j = 0; j < 4; j++) bias[j] = bup[e * HH + n0 + wn + j * 16 + mrow];
#pragma unroll
    for (int i = 0; i < 4; i++) {
#pragma unroll
        for (int r = 0; r < 4; r++) {
            int m = m0 + wm + i * 16 + kq * 4 + r;
            if (m < cnt) {
                unsigned short* hrow = hbuf + (size_t)(off_e + m) * HH + n0 + wn + mrow;
#pragma unroll
                for (int j = 0; j < 4; j++) {
                    float v = acc[i][j][r] + bias[j];
                    v = v / (1.f + __expf(-v));   // silu
                    hrow[j * 16] = f2bf(v);
                }
            }
        }
    }
}

// ---- down GEMM, split-K x2: out[token] += h @ Wdown[e]^T (+ bdown on s==0) ----
__global__ __launch_bounds__(256) void down_gemm(const unsigned short* __restrict__ hbuf,
                                                 const unsigned short* __restrict__ Wdb,
                                                 const float* __restrict__ bdown,
                                                 const int* __restrict__ counts,
                                                 const int* __restrict__ tlist,
                                                 const int* __restrict__ offsets,
                                                 float* __restrict__ out) {
    const int e = blockIdx.z >> 1;
    const int s = blockIdx.z & 1;
    const int cnt = counts[e];
    const int m0 = blockIdx.y * 128;
    if (m0 >= cnt) return;
    const int n0 = blockIdx.x * 128;
    const int t = threadIdx.x;

    __shared__ unsigned short sA[128 * 32];
    __shared__ unsigned short sB[128 * 32];

    const int r0 = t >> 2;
    const int kc = t & 3;
    const int off_e = offsets[e];
    const int c1 = cnt - 1;
    int ra = m0 + r0;      if (ra > c1) ra = c1;
    int rb = m0 + 64 + r0; if (rb > c1) rb = c1;
    const unsigned short* gA0 = hbuf + (size_t)(off_e + ra) * HH + kc * 8;
    const unsigned short* gA1 = hbuf + (size_t)(off_e + rb) * HH + kc * 8;
    const unsigned short* gB0 = Wdb + ((size_t)e * DD + n0 + r0) * HH + kc * 8;
    const unsigned short* gB1 = Wdb + ((size_t)e * DD + n0 + 64 + r0) * HH + kc * 8;
    unsigned short* lA0 = sA + t * 8;
    unsigned short* lA1 = sA + (t + 256) * 8;
    unsigned short* lB0 = sB + t * 8;
    unsigned short* lB1 = sB + (t + 256) * 8;

    const int lane = t & 63;
    const int wm = ((t >> 6) & 1) * 64;
    const int wn = (t >> 7) * 64;
    const int mrow = lane & 15;
    const int kq = lane >> 4;

    f32x4 acc[4][4];
#pragma unroll
    for (int i = 0; i < 4; i++)
#pragma unroll
        for (int j = 0; j < 4; j++)
            acc[i][j] = (f32x4){0.f, 0.f, 0.f, 0.f};

    const int kbeg = s * (HH / 2);
    const int kend = kbeg + (HH / 2);
    for (int kt = kbeg; kt < kend; kt += 32) {
        __syncthreads();
        gload_lds16(gA0 + kt, lA0);
        gload_lds16(gA1 + kt, lA1);
        gload_lds16(gB0 + kt, lB0);
        gload_lds16(gB1 + kt, lB1);
        __syncthreads();
        short8 a[4], b[4];
#pragma unroll
        for (int i = 0; i < 4; i++) {
            a[i] = *(const short8*)(sA + (wm + i * 16 + mrow) * 32 + kq * 8);
            b[i] = *(const short8*)(sB + (wn + i * 16 + mrow) * 32 + kq * 8);
        }
#pragma unroll
        for (int i = 0; i < 4; i++)
#pragma unroll
            for (int j = 0; j < 4; j++)
                acc[i][j] = __builtin_amdgcn_mfma_f32_16x16x32_bf16(a[i], b[j], acc[i][j], 0, 0, 0);
    }

    const int* tl = tlist + e * NT;
    float bias[4];
#pragma unroll
    for (int j = 0; j < 4; j++)
        bias[j] = (s == 0) ? bdown[e * DD + n0 + wn + j * 16 + mrow] : 0.f;
#pragma unroll
    for (int i = 0; i < 4; i++) {
#pragma unroll
        for (int r = 0; r < 4; r++) {
            int m = m0 + wm + i * 16 + kq * 4 + r;
            if (m < cnt) {
                int token = tl[m];
                float* orow = out + (size_t)token * DD + n0 + wn + mrow;
#pragma unroll
                for (int j = 0; j < 4; j++)
                    atomicAdd(&orow[j * 16], acc[i][j][r] + bias[j]);
            }
        }
    }
}

extern "C" void kernel_launch(void* const* d_in, const int* in_sizes, int n_in,
                              void* d_out, int out_size, void* d_ws, size_t ws_size,
                              hipStream_t stream) {
    const float* x     = (const float*)d_in[0];
    const float* Wr    = (const float*)d_in[1];
    const float* br    = (const float*)d_in[2];
    const float* Wup   = (const float*)d_in[3];
    const float* bup   = (const float*)d_in[4];
    const float* Wdown = (const float*)d_in[5];
    const float* bdown = (const float*)d_in[6];
    float* out = (float*)d_out;

    char* w = (char*)d_ws;
    int* counts  = (int*)w;               w += 256;
    int* offsets = (int*)w;               w += 256;
    int* tlist   = (int*)w;               w += (size_t)EE * NT * 4;
    unsigned short* xg   = (unsigned short*)w;  w += (size_t)NT * DD * 2;
    unsigned short* hbuf = (unsigned short*)w;  w += (size_t)NT * HH * 2;
    unsigned short* Wub  = (unsigned short*)w;  w += (size_t)EE * HH * DD * 2;
    unsigned short* Wdb  = (unsigned short*)w;

    hipMemsetAsync(counts, 0, EE * sizeof(int), stream);
    hipMemsetAsync(out, 0, (size_t)NT * DD * sizeof(float), stream);

    cvtw_kernel<<<(2 * (size_t)EE * HH * DD) / 1024, 256, 0, stream>>>(Wup, Wdown, Wub, Wdb);
    router_kernel<<<NT / 4, 256, 0, stream>>>(x, Wr, br, counts, tlist);
    offsets_kernel<<<1, 64, 0, stream>>>(counts, offsets);
    gather_kernel<<<NT / 4, 256, 0, stream>>>(x, tlist, offsets, xg);

    dim3 gu(HH / 128, NT / 128, EE);
    up_gemm<<<gu, 256, 0, stream>>>(xg, Wub, bup, counts, offsets, hbuf);
    dim3 gd(DD / 128, NT / 128, EE * 2);
    down_gemm<<<gd, 256, 0, stream>>>(hbuf, Wdb, bdown, counts, tlist, offsets, out);
}

// Round 3
// 658.960 us; speedup vs baseline: 1.0620x; 1.0620x over previous
//
#include <hip/hip_runtime.h>

#define NT 8192
#define DD 1024
#define HH 4096
#define EE 8

typedef __attribute__((ext_vector_type(8))) short short8;
typedef __attribute__((ext_vector_type(4))) float f32x4;

__device__ __forceinline__ unsigned short f2bf(float f) {
    unsigned int u = __float_as_uint(f);
    u += 0x7FFFu + ((u >> 16) & 1u);   // round-to-nearest-even
    return (unsigned short)(u >> 16);
}

__device__ __forceinline__ void gload_lds16(const void* g, void* l) {
    __builtin_amdgcn_global_load_lds(
        (const __attribute__((address_space(1))) unsigned int*)g,
        (__attribute__((address_space(3))) unsigned int*)l, 16, 0, 0);
}

// ---- fp32 -> bf16 convert for BOTH weight tensors in one launch ----
__global__ __launch_bounds__(256) void cvtw_kernel(const float* __restrict__ a,
                                                   const float* __restrict__ b,
                                                   unsigned short* __restrict__ da,
                                                   unsigned short* __restrict__ db) {
    const size_t half = (size_t)EE * HH * DD;
    size_t i = ((size_t)blockIdx.x * 256 + threadIdx.x) * 4;
    const float* s; unsigned short* d;
    if (i < half) { s = a + i; d = da + i; }
    else          { s = b + (i - half); d = db + (i - half); }
    float4 v = *(const float4*)s;
    ushort4 o;
    o.x = f2bf(v.x); o.y = f2bf(v.y); o.z = f2bf(v.z); o.w = f2bf(v.w);
    *(ushort4*)d = o;
}

// ---- router: one wave per token; argmax of x @ Wr^T + br ----
__global__ __launch_bounds__(256) void router_kernel(const float* __restrict__ x,
                                                     const float* __restrict__ Wr,
                                                     const float* __restrict__ br,
                                                     int* __restrict__ counts,
                                                     int* __restrict__ tlist) {
    __shared__ float sW[EE * DD];  // 32 KB
    const int t = threadIdx.x;
    for (int i = t; i < EE * DD / 4; i += 256)
        ((float4*)sW)[i] = ((const float4*)Wr)[i];
    __syncthreads();
    const int lane = t & 63;
    const int wv = t >> 6;
    const int token = blockIdx.x * 4 + wv;
    const float* xr = x + (size_t)token * DD;
    float acc[EE];
#pragma unroll
    for (int e = 0; e < EE; e++) acc[e] = 0.f;
    for (int k = lane; k < DD; k += 64) {
        float xv = xr[k];
#pragma unroll
        for (int e = 0; e < EE; e++) acc[e] += xv * sW[e * DD + k];
    }
#pragma unroll
    for (int off = 32; off > 0; off >>= 1) {
#pragma unroll
        for (int e = 0; e < EE; e++) acc[e] += __shfl_xor(acc[e], off);
    }
    if (lane == 0) {
        int best = 0;
        float bv = acc[0] + br[0];
#pragma unroll
        for (int e = 1; e < EE; e++) {
            float v = acc[e] + br[e];
            if (v > bv) { bv = v; best = e; }   // strict > == first-max (jnp.argmax)
        }
        int pos = atomicAdd(&counts[best], 1);
        tlist[best * NT + pos] = token;
    }
}

// ---- gather x rows into expert-sorted order, fp32 -> bf16 ----
__global__ __launch_bounds__(256) void gather_kernel(const float* __restrict__ x,
                                                     const int* __restrict__ tlist,
                                                     const int* __restrict__ counts,
                                                     unsigned short* __restrict__ xg) {
    const int row = blockIdx.x * 4 + (threadIdx.x >> 6);
    const int lane = threadIdx.x & 63;
    int off[EE];
    int s = 0;
#pragma unroll
    for (int k = 0; k < EE; k++) { off[k] = s; s += counts[k]; }
    int e = 0;
#pragma unroll
    for (int k = 1; k < EE; k++)
        if (row >= off[k]) e = k;
    const int token = tlist[e * NT + row - off[e]];
    const float4* src = (const float4*)(x + (size_t)token * DD);
    ushort4* dst = (ushort4*)(xg + (size_t)row * DD);
#pragma unroll
    for (int it = 0; it < 4; it++) {
        float4 v = src[it * 64 + lane];
        ushort4 o;
        o.x = f2bf(v.x); o.y = f2bf(v.y); o.z = f2bf(v.z); o.w = f2bf(v.w);
        dst[it * 64 + lane] = o;
    }
}

// LDS layout (both GEMMs): rows of 32 bf16 (64 B); logical 8-elem chunk k of
// row r is stored at slot k ^ ((r>>1)&3). Staging writes stay contiguous
// (global_load_lds constraint); fragment reads become 2-way (free) instead of
// 8-way bank conflicts.

// ---- up GEMM: h = silu(xg @ Wup[e]^T + bup[e]), contiguous A, bf16 out ----
__global__ __launch_bounds__(256) void up_gemm(const unsigned short* __restrict__ xg,
                                               const unsigned short* __restrict__ Wub,
                                               const float* __restrict__ bup,
                                               const int* __restrict__ counts,
                                               unsigned short* __restrict__ hbuf) {
    const int e = blockIdx.z;
    int off_e = 0, cnt;
    {
        int s = 0;
#pragma unroll
        for (int k = 0; k < EE; k++) { if (k == e) off_e = s; s += counts[k]; }
        cnt = counts[e];
    }
    const int m0 = blockIdx.y * 128;
    if (m0 >= cnt) return;
    const int n0 = blockIdx.x * 128;
    const int t = threadIdx.x;

    __shared__ unsigned short sA[128 * 32];
    __shared__ unsigned short sB[128 * 32];

    const int r0 = t >> 2;                      // row within 64-row half
    const int kc = (t & 3) ^ ((r0 >> 1) & 3);   // swizzled chunk this thread fetches
    const int c1 = cnt - 1;
    int ra = m0 + r0;      if (ra > c1) ra = c1;   // clamp tail rows (masked on store)
    int rb = m0 + 64 + r0; if (rb > c1) rb = c1;
    const unsigned short* gA0 = xg + (size_t)(off_e + ra) * DD + kc * 8;
    const unsigned short* gA1 = xg + (size_t)(off_e + rb) * DD + kc * 8;
    const unsigned short* gB0 = Wub + ((size_t)e * HH + n0 + r0) * DD + kc * 8;
    const unsigned short* gB1 = Wub + ((size_t)e * HH + n0 + 64 + r0) * DD + kc * 8;
    unsigned short* lA0 = sA + t * 8;
    unsigned short* lA1 = sA + (t + 256) * 8;
    unsigned short* lB0 = sB + t * 8;
    unsigned short* lB1 = sB + (t + 256) * 8;

    const int lane = t & 63;
    const int wm = ((t >> 6) & 1) * 64;
    const int wn = (t >> 7) * 64;
    const int mrow = lane & 15;
    const int kq = lane >> 4;
    const int slot = (kq ^ ((mrow >> 1) & 3)) * 8;   // swizzled read slot

    f32x4 acc[4][4];
#pragma unroll
    for (int i = 0; i < 4; i++)
#pragma unroll
        for (int j = 0; j < 4; j++)
            acc[i][j] = (f32x4){0.f, 0.f, 0.f, 0.f};

    for (int kt = 0; kt < DD; kt += 32) {
        __syncthreads();
        gload_lds16(gA0 + kt, lA0);
        gload_lds16(gA1 + kt, lA1);
        gload_lds16(gB0 + kt, lB0);
        gload_lds16(gB1 + kt, lB1);
        __syncthreads();
        short8 a[4], b[4];
#pragma unroll
        for (int i = 0; i < 4; i++) {
            a[i] = *(const short8*)(sA + (wm + i * 16 + mrow) * 32 + slot);
            b[i] = *(const short8*)(sB + (wn + i * 16 + mrow) * 32 + slot);
        }
#pragma unroll
        for (int i = 0; i < 4; i++)
#pragma unroll
            for (int j = 0; j < 4; j++)
                acc[i][j] = __builtin_amdgcn_mfma_f32_16x16x32_bf16(a[i], b[j], acc[i][j], 0, 0, 0);
    }

    float bias[4];
#pragma unroll
    for (int j = 0; j < 4; j++) bias[j] = bup[e * HH + n0 + wn + j * 16 + mrow];
#pragma unroll
    for (int i = 0; i < 4; i++) {
#pragma unroll
        for (int r = 0; r < 4; r++) {
            int m = m0 + wm + i * 16 + kq * 4 + r;
            if (m < cnt) {
                unsigned short* hrow = hbuf + (size_t)(off_e + m) * HH + n0 + wn + mrow;
#pragma unroll
                for (int j = 0; j < 4; j++) {
                    float v = acc[i][j][r] + bias[j];
                    v = v / (1.f + __expf(-v));   // silu
                    hrow[j * 16] = f2bf(v);
                }
            }
        }
    }
}

// ---- down GEMM: out[token] = h @ Wdown[e]^T + bdown[e], fp32 scatter-out ----
__global__ __launch_bounds__(256) void down_gemm(const unsigned short* __restrict__ hbuf,
                                                 const unsigned short* __restrict__ Wdb,
                                                 const float* __restrict__ bdown,
                                                 const int* __restrict__ counts,
                                                 const int* __restrict__ tlist,
                                                 float* __restrict__ out) {
    const int e = blockIdx.z;
    int off_e = 0, cnt;
    {
        int s = 0;
#pragma unroll
        for (int k = 0; k < EE; k++) { if (k == e) off_e = s; s += counts[k]; }
        cnt = counts[e];
    }
    const int m0 = blockIdx.y * 128;
    if (m0 >= cnt) return;
    const int n0 = blockIdx.x * 128;
    const int t = threadIdx.x;

    __shared__ unsigned short sA[128 * 32];
    __shared__ unsigned short sB[128 * 32];

    const int r0 = t >> 2;
    const int kc = (t & 3) ^ ((r0 >> 1) & 3);
    const int c1 = cnt - 1;
    int ra = m0 + r0;      if (ra > c1) ra = c1;
    int rb = m0 + 64 + r0; if (rb > c1) rb = c1;
    const unsigned short* gA0 = hbuf + (size_t)(off_e + ra) * HH + kc * 8;
    const unsigned short* gA1 = hbuf + (size_t)(off_e + rb) * HH + kc * 8;
    const unsigned short* gB0 = Wdb + ((size_t)e * DD + n0 + r0) * HH + kc * 8;
    const unsigned short* gB1 = Wdb + ((size_t)e * DD + n0 + 64 + r0) * HH + kc * 8;
    unsigned short* lA0 = sA + t * 8;
    unsigned short* lA1 = sA + (t + 256) * 8;
    unsigned short* lB0 = sB + t * 8;
    unsigned short* lB1 = sB + (t + 256) * 8;

    const int lane = t & 63;
    const int wm = ((t >> 6) & 1) * 64;
    const int wn = (t >> 7) * 64;
    const int mrow = lane & 15;
    const int kq = lane >> 4;
    const int slot = (kq ^ ((mrow >> 1) & 3)) * 8;

    f32x4 acc[4][4];
#pragma unroll
    for (int i = 0; i < 4; i++)
#pragma unroll
        for (int j = 0; j < 4; j++)
            acc[i][j] = (f32x4){0.f, 0.f, 0.f, 0.f};

    for (int kt = 0; kt < HH; kt += 32) {
        __syncthreads();
        gload_lds16(gA0 + kt, lA0);
        gload_lds16(gA1 + kt, lA1);
        gload_lds16(gB0 + kt, lB0);
        gload_lds16(gB1 + kt, lB1);
        __syncthreads();
        short8 a[4], b[4];
#pragma unroll
        for (int i = 0; i < 4; i++) {
            a[i] = *(const short8*)(sA + (wm + i * 16 + mrow) * 32 + slot);
            b[i] = *(const short8*)(sB + (wn + i * 16 + mrow) * 32 + slot);
        }
#pragma unroll
        for (int i = 0; i < 4; i++)
#pragma unroll
            for (int j = 0; j < 4; j++)
                acc[i][j] = __builtin_amdgcn_mfma_f32_16x16x32_bf16(a[i], b[j], acc[i][j], 0, 0, 0);
    }

    const int* tl = tlist + e * NT;
    float bias[4];
#pragma unroll
    for (int j = 0; j < 4; j++) bias[j] = bdown[e * DD + n0 + wn + j * 16 + mrow];
#pragma unroll
    for (int i = 0; i < 4; i++) {
#pragma unroll
        for (int r = 0; r < 4; r++) {
            int m = m0 + wm + i * 16 + kq * 4 + r;
            if (m < cnt) {
                int token = tl[m];
                float* orow = out + (size_t)token * DD + n0 + wn + mrow;
#pragma unroll
                for (int j = 0; j < 4; j++)
                    orow[j * 16] = acc[i][j][r] + bias[j];
            }
        }
    }
}

extern "C" void kernel_launch(void* const* d_in, const int* in_sizes, int n_in,
                              void* d_out, int out_size, void* d_ws, size_t ws_size,
                              hipStream_t stream) {
    const float* x     = (const float*)d_in[0];
    const float* Wr    = (const float*)d_in[1];
    const float* br    = (const float*)d_in[2];
    const float* Wup   = (const float*)d_in[3];
    const float* bup   = (const float*)d_in[4];
    const float* Wdown = (const float*)d_in[5];
    const float* bdown = (const float*)d_in[6];
    float* out = (float*)d_out;

    char* w = (char*)d_ws;
    int* counts  = (int*)w;               w += 256;
    int* tlist   = (int*)w;               w += (size_t)EE * NT * 4;
    unsigned short* xg   = (unsigned short*)w;  w += (size_t)NT * DD * 2;
    unsigned short* hbuf = (unsigned short*)w;  w += (size_t)NT * HH * 2;
    unsigned short* Wub  = (unsigned short*)w;  w += (size_t)EE * HH * DD * 2;
    unsigned short* Wdb  = (unsigned short*)w;

    hipMemsetAsync(counts, 0, EE * sizeof(int), stream);

    cvtw_kernel<<<(2 * (size_t)EE * HH * DD) / 1024, 256, 0, stream>>>(Wup, Wdown, Wub, Wdb);
    router_kernel<<<NT / 4, 256, 0, stream>>>(x, Wr, br, counts, tlist);
    gather_kernel<<<NT / 4, 256, 0, stream>>>(x, tlist, counts, xg);

    dim3 gu(HH / 128, NT / 128, EE);
    up_gemm<<<gu, 256, 0, stream>>>(xg, Wub, bup, counts, hbuf);
    dim3 gd(DD / 128, NT / 128, EE);
    down_gemm<<<gd, 256, 0, stream>>>(hbuf, Wdb, bdown, counts, tlist, out);
}